// Round 2
// baseline (660.201 us; speedup 1.0000x reference)
//
// Ernie4.5 MoE MLP — MI355X gfx950
// Pipeline: gate(fp32 VALU) -> hist/scan/place (exact token-major capacity order)
//        -> dispatch x->bf16 -> gemm1 (fused g,u + SwiGLU, bf16 MFMA, tr_b16 B-frags)
//        -> gemm2 (down proj) -> combine (weighted gather).
// ws usage ~126.4 MB. expert_out aliases the dispatch buffer (dead after gemm1).
// R2 fix: ds_read_b64_tr_b16 addressing = per-lane base + 8*lane with the four
//         lane-group subtiles stored consecutively (robust under all plausible
//         tr-read models); wave-uniform LDS dest for global_load_lds; XCD-chunked
//         block swizzle (mt innermost) for weight-panel L2 reuse.
#include <hip/hip_runtime.h>
#include <hip/hip_bf16.h>

constexpr int S_TOK = 16384;
constexpr int HDIM  = 1024;
constexpr int IDIM  = 512;
constexpr int NEXP  = 64;
constexpr int CAPC  = 640;
constexpr int NCHUNK = 128;   // 32768 routing entries / 256

typedef __attribute__((ext_vector_type(8))) short bf16x8;
typedef __attribute__((ext_vector_type(4))) short short4v;
typedef __attribute__((ext_vector_type(4))) float f32x4;

__device__ __forceinline__ float bf2f(unsigned short u){
  return __uint_as_float(((unsigned)u) << 16);
}
__device__ __forceinline__ unsigned short f2bf(float f){   // RNE bf16 (inputs finite)
  unsigned u = __float_as_uint(f);
  return (unsigned short)((u + 0x7fffu + ((u >> 16) & 1u)) >> 16);
}
__device__ __forceinline__ unsigned pk2(float a, float b){
  return (unsigned)f2bf(a) | ((unsigned)f2bf(b) << 16);
}
__device__ __forceinline__ void gload_lds16(const void* g, void* l){
  __builtin_amdgcn_global_load_lds((const __attribute__((address_space(1))) unsigned*)g,
                                   (__attribute__((address_space(3))) unsigned*)l, 16, 0, 0);
}
__device__ __forceinline__ unsigned ldsoff(const void* p){ return (unsigned)(size_t)p; }
// two hw-transpose reads: k-slots 0..3 (parity 0) and 4..7 (parity 1, +4 blocks=512B)
__device__ __forceinline__ void trread2(unsigned addr, short4v& lo, short4v& hi){
  asm volatile("ds_read_b64_tr_b16 %0, %2\n\t"
               "ds_read_b64_tr_b16 %1, %2 offset:512"
               : "=&v"(lo), "=&v"(hi) : "v"(addr));
}

// ---------------- gate: logits (fp32 exact), softmax, top-2 -------------------
__global__ __launch_bounds__(256) void gate_kernel(
    const float* __restrict__ x, const float* __restrict__ wgate,
    float* __restrict__ logits_out, float* __restrict__ topk_p,
    int* __restrict__ flat_e, float* __restrict__ rl_out)
{
  __shared__ float xs[4][HDIM];
  const int w = threadIdx.x >> 6, lane = threadIdx.x & 63;
  const int tok = blockIdx.x * 4 + w;
  const float4* xr = (const float4*)(x + (size_t)tok * HDIM);
  float4* xd = (float4*)(&xs[w][0]);
#pragma unroll
  for (int j = 0; j < 4; ++j) xd[j * 64 + lane] = xr[j * 64 + lane];
  __syncthreads();
  float acc = 0.f;
#pragma unroll 8
  for (int h = 0; h < HDIM; ++h)
    acc = fmaf(xs[w][h], wgate[h * NEXP + lane], acc);
  logits_out[(size_t)tok * NEXP + lane] = acc;
  // softmax over 64 lanes
  float m = acc;
#pragma unroll
  for (int d = 1; d < 64; d <<= 1) m = fmaxf(m, __shfl_xor(m, d));
  float p = expf(acc - m);
  float sum = p;
#pragma unroll
  for (int d = 1; d < 64; d <<= 1) sum += __shfl_xor(sum, d);
  float prob = p / sum;
  // top-1 (ties -> lower index, matches lax.top_k)
  float v = prob; int idx = lane;
#pragma unroll
  for (int d = 1; d < 64; d <<= 1){
    float ov = __shfl_xor(v, d); int oi = __shfl_xor(idx, d);
    if (ov > v || (ov == v && oi < idx)){ v = ov; idx = oi; }
  }
  const int e1 = idx; const float p1 = v;
  v = (lane == e1) ? -1.f : prob; idx = lane;
#pragma unroll
  for (int d = 1; d < 64; d <<= 1){
    float ov = __shfl_xor(v, d); int oi = __shfl_xor(idx, d);
    if (ov > v || (ov == v && oi < idx)){ v = ov; idx = oi; }
  }
  if (lane == 0){
    flat_e[tok * 2]     = e1;  flat_e[tok * 2 + 1] = idx;
    topk_p[tok * 2]     = p1;  topk_p[tok * 2 + 1] = v;
  }
  if (tok == 0 && lane == 0) rl_out[0] = 0.f;
}

// ---------------- per-chunk expert histogram ---------------------------------
__global__ __launch_bounds__(256) void hist_kernel(const int* __restrict__ flat_e,
                                                   int* __restrict__ counts)
{
  __shared__ int hh[NEXP];
  const int t = threadIdx.x;
  if (t < NEXP) hh[t] = 0;
  __syncthreads();
  const int e = flat_e[blockIdx.x * 256 + t];
  atomicAdd(&hh[e], 1);
  __syncthreads();
  if (t < NEXP) counts[blockIdx.x * NEXP + t] = hh[t];
}

// ---------------- per-expert exclusive scan over chunks ----------------------
__global__ __launch_bounds__(256) void offsets_kernel(const int* __restrict__ counts,
                                                      int* __restrict__ offs,
                                                      int* __restrict__ etot)
{
  const int w = threadIdx.x >> 6, lane = threadIdx.x & 63;
  const int e = blockIdx.x * 4 + w;
  int v0 = counts[lane * NEXP + e];
  int v1 = counts[(64 + lane) * NEXP + e];
  int s0 = v0, s1 = v1;
#pragma unroll
  for (int d = 1; d < 64; d <<= 1){
    int n0 = __shfl_up(s0, d); if (lane >= d) s0 += n0;
    int n1 = __shfl_up(s1, d); if (lane >= d) s1 += n1;
  }
  const int tot0 = __shfl(s0, 63);
  offs[lane * NEXP + e]        = s0 - v0;
  offs[(64 + lane) * NEXP + e] = tot0 + s1 - v1;
  if (lane == 63) etot[e] = tot0 + s1;
}

// ---------------- ordered placement + slot map + cw --------------------------
__global__ __launch_bounds__(256) void place_kernel(
    const int* __restrict__ flat_e, const float* __restrict__ topk_p,
    const int* __restrict__ offs, int* __restrict__ entry_slot,
    int* __restrict__ token_of_slot, float* __restrict__ cw_out)
{
  __shared__ int es[256];
  __shared__ float wsh[256];
  const int t = threadIdx.x;
  const int i = blockIdx.x * 256 + t;
  const int e = flat_e[i];
  es[t] = e;
  __syncthreads();
  int local = 0;
  for (int j = 0; j < t; ++j) local += (es[j] == e);   // uniform-j broadcast reads
  const int pos = offs[blockIdx.x * NEXP + e] + local;
  const bool valid = pos < CAPC;
  const int slot = e * CAPC + pos;
  entry_slot[i] = valid ? slot : -1;
  if (valid) token_of_slot[slot] = i >> 1;
  const float p = topk_p[i];
  wsh[t] = valid ? p : 0.f;
  __syncthreads();
  const float wme = wsh[t], wo = wsh[t ^ 1];
  cw_out[i] = wme / fmaxf(wme + wo, 1e-12f);
}

// ---------------- build dispatched A (bf16) ----------------------------------
__global__ __launch_bounds__(256) void adisp_kernel(
    const float* __restrict__ x, const int* __restrict__ token_of_slot,
    const int* __restrict__ etot, unsigned short* __restrict__ adisp)
{
  const int slot = blockIdx.x;
  const int e = slot / CAPC, c = slot - e * CAPC;
  int cnt = etot[e]; if (cnt > CAPC) cnt = CAPC;
  if (c >= cnt) return;                    // empty slots stay garbage (never read)
  const int tok = token_of_slot[slot];
  const int t = threadIdx.x;
  float4 v = ((const float4*)(x + (size_t)tok * HDIM))[t];
  ushort4 o; o.x = f2bf(v.x); o.y = f2bf(v.y); o.z = f2bf(v.z); o.w = f2bf(v.w);
  ((ushort4*)(adisp + (size_t)slot * HDIM))[t] = o;
}

// B-tile LDS layout (64k x 128n, bf16): 4x16 subtiles, storage block index
//   ((ks*8 + ng)*2 + parity)*4 + g   where k = 32*ks + 8*g + 4*parity + dk.
// One tr_read pair per (ks, cg): addr = (ks*8+cg)*1024 + 8*lane, offset:512 for
// parity 1. Gives lane l slots j: B[32ks + 8*(l>>4) + j][cg*16 + (l&15)].

// ---------------- gemm1: fused g,u = A*Wg, A*Wu ; h = silu(g)*u (bf16) -------
__global__ __launch_bounds__(256) void gemm1_kernel(
    const unsigned short* __restrict__ adisp,
    const float* __restrict__ wg, const float* __restrict__ wu,
    unsigned short* __restrict__ hbuf)
{
  __shared__ unsigned short As[128 * 64];    // swizzled row-major [row][j^(row&7)]
  __shared__ unsigned short Bgs[64 * 128];   // subtiled for tr_b16 reads
  __shared__ unsigned short Bus[64 * 128];
  // XCD-chunked swizzle: consecutive logical blocks land on one XCD; mt innermost
  const int bb = blockIdx.x;
  const int lb = (bb & 7) * 160 + (bb >> 3);         // 1280 blocks, 1280%8==0
  const int e = lb / 20; const int r2 = lb - e * 20;
  const int nt = r2 / 5, mt = r2 - nt * 5;           // mt innermost: 5 blocks share B
  const int t = threadIdx.x, w = t >> 6, lane = t & 63;
  const int wr = w >> 1, wc = w & 1;
  const size_t arow0 = (size_t)e * CAPC + (size_t)mt * 128;
  const float* wgp = wg + (size_t)e * HDIM * IDIM + nt * 128;
  const float* wup = wu + (size_t)e * HDIM * IDIM + nt * 128;

  f32x4 accg[4][4], accu[4][4];
#pragma unroll
  for (int i = 0; i < 4; ++i)
#pragma unroll
    for (int j = 0; j < 4; ++j)
#pragma unroll
      for (int q = 0; q < 4; ++q){ accg[i][j][q] = 0.f; accu[i][j][q] = 0.f; }

  const int dk = lane & 3, h8 = (lane >> 2) & 1, ng = lane >> 3;

  for (int kb = 0; kb < HDIM; kb += 64){
    __syncthreads();
    // A: global_load_lds, wave-uniform dest base (+lane*16 implicit), source
    // pre-swizzled (rule 21)
#pragma unroll
    for (int rr = 0; rr < 4; ++rr){
      int c = rr * 256 + t;
      int row = c >> 3;
      int jsrc = (c & 7) ^ (row & 7);
      gload_lds16(adisp + (arow0 + row) * HDIM + kb + jsrc * 8,
                  &As[(rr * 256 + w * 64) * 8]);
    }
    // B (both): fp32 load -> bf16 pack -> subtiled LDS, bank-even mapping
#pragma unroll
    for (int rr = 0; rr < 4; ++rr){
      int kq = w * 4 + rr;
      const size_t go = (size_t)(kb + kq * 4 + dk) * IDIM + ng * 16 + h8 * 8;
      const float* gp = wgp + go;
      const float* up = wup + go;
      float4 g0 = *(const float4*)gp, g1 = *(const float4*)(gp + 4);
      float4 u0 = *(const float4*)up, u1 = *(const float4*)(up + 4);
      int ksb = kq >> 3, par = kq & 1, g = (kq >> 1) & 3;
      unsigned off = (unsigned)(((((ksb * 8 + ng) * 2 + par) * 4 + g) * 64) + dk * 16 + h8 * 8);
      *(uint4*)&Bgs[off] = make_uint4(pk2(g0.x,g0.y), pk2(g0.z,g0.w), pk2(g1.x,g1.y), pk2(g1.z,g1.w));
      *(uint4*)&Bus[off] = make_uint4(pk2(u0.x,u0.y), pk2(u0.z,u0.w), pk2(u1.x,u1.y), pk2(u1.z,u1.w));
    }
    __syncthreads();

    const unsigned bg0 = ldsoff(Bgs), bu0 = ldsoff(Bus);
#pragma unroll
    for (int ks = 0; ks < 2; ++ks){
      bf16x8 af[4];
#pragma unroll
      for (int m = 0; m < 4; ++m){
        int row = wr * 64 + m * 16 + (lane & 15);
        int j = ks * 4 + (lane >> 4);
        af[m] = *(const bf16x8*)&As[row * 64 + ((j ^ (row & 7)) * 8)];
      }
      bf16x8 bgf[4], buf_[4];
#pragma unroll
      for (int n = 0; n < 4; ++n){
        int cg = wc * 4 + n;
        unsigned ao = (unsigned)((ks * 8 + cg) * 1024 + lane * 8);
        short4v l0, l1, m0, m1;
        trread2(bg0 + ao, l0, l1);
        trread2(bu0 + ao, m0, m1);
        bgf[n]  = __builtin_shufflevector(l0, l1, 0,1,2,3,4,5,6,7);
        buf_[n] = __builtin_shufflevector(m0, m1, 0,1,2,3,4,5,6,7);
      }
      asm volatile("s_waitcnt lgkmcnt(0)" ::: "memory");
      __builtin_amdgcn_sched_barrier(0);
#pragma unroll
      for (int m = 0; m < 4; ++m)
#pragma unroll
        for (int n = 0; n < 4; ++n){
          accg[m][n] = __builtin_amdgcn_mfma_f32_16x16x32_bf16(af[m], bgf[n],  accg[m][n], 0, 0, 0);
          accu[m][n] = __builtin_amdgcn_mfma_f32_16x16x32_bf16(af[m], buf_[n], accu[m][n], 0, 0, 0);
        }
    }
  }
  // epilogue: h = silu(g)*u -> bf16
#pragma unroll
  for (int m = 0; m < 4; ++m)
#pragma unroll
    for (int n = 0; n < 4; ++n)
#pragma unroll
      for (int q = 0; q < 4; ++q){
        int row = wr * 64 + m * 16 + (lane >> 4) * 4 + q;
        int col = nt * 128 + wc * 64 + n * 16 + (lane & 15);
        float gv = accg[m][n][q], uv = accu[m][n][q];
        float hv = gv / (1.f + expf(-gv)) * uv;
        hbuf[(arow0 + row) * IDIM + col] = f2bf(hv);
      }
}

// ---------------- gemm2: eo = h * Wd (bf16 out) ------------------------------
__global__ __launch_bounds__(256) void gemm2_kernel(
    const unsigned short* __restrict__ hbuf,
    const float* __restrict__ wd,
    unsigned short* __restrict__ eo)
{
  __shared__ unsigned short As[128 * 64];
  __shared__ unsigned short Bs[64 * 128];
  const int bb = blockIdx.x;
  const int lb = (bb & 7) * 320 + (bb >> 3);         // 2560 blocks, 2560%8==0
  const int e = lb / 40; const int r2 = lb - e * 40;
  const int nt = r2 / 5, mt = r2 - nt * 5;           // mt innermost: 5 blocks share B
  const int t = threadIdx.x, w = t >> 6, lane = t & 63;
  const int wr = w >> 1, wc = w & 1;
  const size_t arow0 = (size_t)e * CAPC + (size_t)mt * 128;
  const float* wdp = wd + (size_t)e * IDIM * HDIM + nt * 128;

  f32x4 acc[4][4];
#pragma unroll
  for (int i = 0; i < 4; ++i)
#pragma unroll
    for (int j = 0; j < 4; ++j)
#pragma unroll
      for (int q = 0; q < 4; ++q) acc[i][j][q] = 0.f;

  const int dk = lane & 3, h8 = (lane >> 2) & 1, ng = lane >> 3;

  for (int kb = 0; kb < IDIM; kb += 64){
    __syncthreads();
#pragma unroll
    for (int rr = 0; rr < 4; ++rr){
      int c = rr * 256 + t;
      int row = c >> 3;
      int jsrc = (c & 7) ^ (row & 7);
      gload_lds16(hbuf + (arow0 + row) * IDIM + kb + jsrc * 8,
                  &As[(rr * 256 + w * 64) * 8]);
    }
#pragma unroll
    for (int rr = 0; rr < 4; ++rr){
      int kq = w * 4 + rr;
      const float* gp = wdp + (size_t)(kb + kq * 4 + dk) * HDIM + ng * 16 + h8 * 8;
      float4 g0 = *(const float4*)gp, g1 = *(const float4*)(gp + 4);
      int ksb = kq >> 3, par = kq & 1, g = (kq >> 1) & 3;
      unsigned off = (unsigned)(((((ksb * 8 + ng) * 2 + par) * 4 + g) * 64) + dk * 16 + h8 * 8);
      *(uint4*)&Bs[off] = make_uint4(pk2(g0.x,g0.y), pk2(g0.z,g0.w), pk2(g1.x,g1.y), pk2(g1.z,g1.w));
    }
    __syncthreads();

    const unsigned b0a = ldsoff(Bs);
#pragma unroll
    for (int ks = 0; ks < 2; ++ks){
      bf16x8 af[4];
#pragma unroll
      for (int m = 0; m < 4; ++m){
        int row = wr * 64 + m * 16 + (lane & 15);
        int j = ks * 4 + (lane >> 4);
        af[m] = *(const bf16x8*)&As[row * 64 + ((j ^ (row & 7)) * 8)];
      }
      bf16x8 bfr[4];
#pragma unroll
      for (int n = 0; n < 4; ++n){
        int cg = wc * 4 + n;
        unsigned ao = (unsigned)((ks * 8 + cg) * 1024 + lane * 8);
        short4v l0, l1;
        trread2(b0a + ao, l0, l1);
        bfr[n] = __builtin_shufflevector(l0, l1, 0,1,2,3,4,5,6,7);
      }
      asm volatile("s_waitcnt lgkmcnt(0)" ::: "memory");
      __builtin_amdgcn_sched_barrier(0);
#pragma unroll
      for (int m = 0; m < 4; ++m)
#pragma unroll
        for (int n = 0; n < 4; ++n)
          acc[m][n] = __builtin_amdgcn_mfma_f32_16x16x32_bf16(af[m], bfr[n], acc[m][n], 0, 0, 0);
    }
  }
#pragma unroll
  for (int m = 0; m < 4; ++m)
#pragma unroll
    for (int n = 0; n < 4; ++n)
#pragma unroll
      for (int q = 0; q < 4; ++q){
        int row = wr * 64 + m * 16 + (lane >> 4) * 4 + q;
        int col = nt * 128 + wc * 64 + n * 16 + (lane & 15);
        eo[(arow0 + row) * HDIM + col] = f2bf(acc[m][n][q]);
      }
}

// ---------------- combine: out[s] = sum_k cw[s,k] * eo[slot(s,k)] ------------
__global__ __launch_bounds__(256) void combine_kernel(
    const unsigned short* __restrict__ eo, const int* __restrict__ entry_slot,
    const float* __restrict__ cw, float* __restrict__ out)
{
  const int s = blockIdx.x, t = threadIdx.x;
  const int s0 = entry_slot[2 * s], s1 = entry_slot[2 * s + 1];
  const float w0 = cw[2 * s], w1 = cw[2 * s + 1];
  const int c = t * 4;
  float r0 = 0.f, r1 = 0.f, r2 = 0.f, r3 = 0.f;
  if (s0 >= 0){
    ushort4 vq = *(const ushort4*)&eo[(size_t)s0 * HDIM + c];
    r0 += w0 * bf2f(vq.x); r1 += w0 * bf2f(vq.y); r2 += w0 * bf2f(vq.z); r3 += w0 * bf2f(vq.w);
  }
  if (s1 >= 0){
    ushort4 vq = *(const ushort4*)&eo[(size_t)s1 * HDIM + c];
    r0 += w1 * bf2f(vq.x); r1 += w1 * bf2f(vq.y); r2 += w1 * bf2f(vq.z); r3 += w1 * bf2f(vq.w);
  }
  ((float4*)(out + (size_t)s * HDIM))[t] = make_float4(r0, r1, r2, r3);
}

extern "C" void kernel_launch(void* const* d_in, const int* in_sizes, int n_in,
                              void* d_out, int out_size, void* d_ws, size_t ws_size,
                              hipStream_t stream) {
  (void)in_sizes; (void)n_in; (void)out_size; (void)ws_size;
  const float* x     = (const float*)d_in[0];
  const float* wgate = (const float*)d_in[1];
  const float* wg    = (const float*)d_in[2];
  const float* wu    = (const float*)d_in[3];
  const float* wd    = (const float*)d_in[4];

  float* out        = (float*)d_out;                         // [S,H]
  float* cw_out     = out + (size_t)S_TOK * HDIM;            // [S,2]
  float* rl_out     = cw_out + (size_t)S_TOK * 2;            // [1]
  float* logits_out = rl_out + 1;                            // [S,64]

  char* w8 = (char*)d_ws;
  size_t off = 0;
  auto alloc = [&](size_t bytes){ size_t r = off; off += (bytes + 255) & ~(size_t)255; return r; };
  int*   flat_e_ws        = (int*)  (w8 + alloc((size_t)32768 * 4));
  float* topk_p_ws        = (float*)(w8 + alloc((size_t)32768 * 4));
  int*   counts_ws        = (int*)  (w8 + alloc((size_t)NCHUNK * NEXP * 4));
  int*   offs_ws          = (int*)  (w8 + alloc((size_t)NCHUNK * NEXP * 4));
  int*   etot_ws          = (int*)  (w8 + alloc((size_t)NEXP * 4));
  int*   entry_slot_ws    = (int*)  (w8 + alloc((size_t)32768 * 4));
  int*   token_of_slot_ws = (int*)  (w8 + alloc((size_t)NEXP * CAPC * 4));
  unsigned short* hbuf_ws = (unsigned short*)(w8 + alloc((size_t)NEXP * CAPC * IDIM * 2));
  unsigned short* adisp_ws= (unsigned short*)(w8 + alloc((size_t)NEXP * CAPC * HDIM * 2));
  unsigned short* eo_ws   = adisp_ws;   // alias: adisp dead after gemm1

  gate_kernel   <<<S_TOK / 4, 256, 0, stream>>>(x, wgate, logits_out, topk_p_ws, flat_e_ws, rl_out);
  hist_kernel   <<<NCHUNK,    256, 0, stream>>>(flat_e_ws, counts_ws);
  offsets_kernel<<<16,        256, 0, stream>>>(counts_ws, offs_ws, etot_ws);
  place_kernel  <<<NCHUNK,    256, 0, stream>>>(flat_e_ws, topk_p_ws, offs_ws,
                                                entry_slot_ws, token_of_slot_ws, cw_out);
  adisp_kernel  <<<NEXP * CAPC, 256, 0, stream>>>(x, token_of_slot_ws, etot_ws, adisp_ws);
  gemm1_kernel  <<<NEXP * 20, 256, 0, stream>>>(adisp_ws, wg, wu, hbuf_ws);
  gemm2_kernel  <<<NEXP * 40, 256, 0, stream>>>(hbuf_ws, wd, eo_ws);
  combine_kernel<<<S_TOK,     256, 0, stream>>>(eo_ws, entry_slot_ws, cw_out, out);
}

// Round 3
// 567.389 us; speedup vs baseline: 1.1636x; 1.1636x over previous
//
// Ernie4.5 MoE MLP — MI355X gfx950
// R3: weights pre-converted to bf16 (one streaming pass); both GEMMs stage A AND B
//     via global_load_lds width-16 (B source pre-swizzled to the tr_b16 subtiled
//     layout, LDS dest linear — rule 21). Removes in-loop fp32->bf16 VALU packing
//     and halves B traffic. wd-bf16 reuses the wg-bf16 buffer after gemm1.
// ws peak ~261 MB. eo aliases adisp (dead after gemm1).
#include <hip/hip_runtime.h>
#include <hip/hip_bf16.h>

constexpr int S_TOK = 16384;
constexpr int HDIM  = 1024;
constexpr int IDIM  = 512;
constexpr int NEXP  = 64;
constexpr int CAPC  = 640;
constexpr int NCHUNK = 128;   // 32768 routing entries / 256

typedef __attribute__((ext_vector_type(8))) short bf16x8;
typedef __attribute__((ext_vector_type(4))) short short4v;
typedef __attribute__((ext_vector_type(4))) float f32x4;

__device__ __forceinline__ float bf2f(unsigned short u){
  return __uint_as_float(((unsigned)u) << 16);
}
__device__ __forceinline__ unsigned short f2bf(float f){   // RNE bf16 (inputs finite)
  unsigned u = __float_as_uint(f);
  return (unsigned short)((u + 0x7fffu + ((u >> 16) & 1u)) >> 16);
}
__device__ __forceinline__ unsigned pk2(float a, float b){
  return (unsigned)f2bf(a) | ((unsigned)f2bf(b) << 16);
}
__device__ __forceinline__ void gload_lds16(const void* g, void* l){
  __builtin_amdgcn_global_load_lds((const __attribute__((address_space(1))) unsigned*)g,
                                   (__attribute__((address_space(3))) unsigned*)l, 16, 0, 0);
}
__device__ __forceinline__ unsigned ldsoff(const void* p){ return (unsigned)(size_t)p; }
// two hw-transpose reads: parity-0 block and parity-1 block (+512B)
__device__ __forceinline__ void trread2(unsigned addr, short4v& lo, short4v& hi){
  asm volatile("ds_read_b64_tr_b16 %0, %2\n\t"
               "ds_read_b64_tr_b16 %1, %2 offset:512"
               : "=&v"(lo), "=&v"(hi) : "v"(addr));
}

// ---------------- weight fp32 -> bf16 streaming convert ----------------------
__global__ __launch_bounds__(256) void wcvt_kernel(const float* __restrict__ src,
                                                   unsigned short* __restrict__ dst,
                                                   int n8)
{
  int i = blockIdx.x * 256 + threadIdx.x;
  const int stride = gridDim.x * 256;
  for (; i < n8; i += stride){
    const float4 a = ((const float4*)src)[2 * i];
    const float4 b = ((const float4*)src)[2 * i + 1];
    *(uint4*)&dst[(size_t)i * 8] =
      make_uint4(pk2(a.x, a.y), pk2(a.z, a.w), pk2(b.x, b.y), pk2(b.z, b.w));
  }
}

// ---------------- gate: logits (fp32 exact), softmax, top-2 -------------------
__global__ __launch_bounds__(256) void gate_kernel(
    const float* __restrict__ x, const float* __restrict__ wgate,
    float* __restrict__ logits_out, float* __restrict__ topk_p,
    int* __restrict__ flat_e, float* __restrict__ rl_out)
{
  __shared__ float xs[4][HDIM];
  const int w = threadIdx.x >> 6, lane = threadIdx.x & 63;
  const int tok = blockIdx.x * 4 + w;
  const float4* xr = (const float4*)(x + (size_t)tok * HDIM);
  float4* xd = (float4*)(&xs[w][0]);
#pragma unroll
  for (int j = 0; j < 4; ++j) xd[j * 64 + lane] = xr[j * 64 + lane];
  __syncthreads();
  float acc = 0.f;
#pragma unroll 8
  for (int h = 0; h < HDIM; ++h)
    acc = fmaf(xs[w][h], wgate[h * NEXP + lane], acc);
  logits_out[(size_t)tok * NEXP + lane] = acc;
  float m = acc;
#pragma unroll
  for (int d = 1; d < 64; d <<= 1) m = fmaxf(m, __shfl_xor(m, d));
  float p = expf(acc - m);
  float sum = p;
#pragma unroll
  for (int d = 1; d < 64; d <<= 1) sum += __shfl_xor(sum, d);
  float prob = p / sum;
  float v = prob; int idx = lane;
#pragma unroll
  for (int d = 1; d < 64; d <<= 1){
    float ov = __shfl_xor(v, d); int oi = __shfl_xor(idx, d);
    if (ov > v || (ov == v && oi < idx)){ v = ov; idx = oi; }
  }
  const int e1 = idx; const float p1 = v;
  v = (lane == e1) ? -1.f : prob; idx = lane;
#pragma unroll
  for (int d = 1; d < 64; d <<= 1){
    float ov = __shfl_xor(v, d); int oi = __shfl_xor(idx, d);
    if (ov > v || (ov == v && oi < idx)){ v = ov; idx = oi; }
  }
  if (lane == 0){
    flat_e[tok * 2]     = e1;  flat_e[tok * 2 + 1] = idx;
    topk_p[tok * 2]     = p1;  topk_p[tok * 2 + 1] = v;
  }
  if (tok == 0 && lane == 0) rl_out[0] = 0.f;
}

// ---------------- per-chunk expert histogram ---------------------------------
__global__ __launch_bounds__(256) void hist_kernel(const int* __restrict__ flat_e,
                                                   int* __restrict__ counts)
{
  __shared__ int hh[NEXP];
  const int t = threadIdx.x;
  if (t < NEXP) hh[t] = 0;
  __syncthreads();
  const int e = flat_e[blockIdx.x * 256 + t];
  atomicAdd(&hh[e], 1);
  __syncthreads();
  if (t < NEXP) counts[blockIdx.x * NEXP + t] = hh[t];
}

// ---------------- per-expert exclusive scan over chunks ----------------------
__global__ __launch_bounds__(256) void offsets_kernel(const int* __restrict__ counts,
                                                      int* __restrict__ offs,
                                                      int* __restrict__ etot)
{
  const int w = threadIdx.x >> 6, lane = threadIdx.x & 63;
  const int e = blockIdx.x * 4 + w;
  int v0 = counts[lane * NEXP + e];
  int v1 = counts[(64 + lane) * NEXP + e];
  int s0 = v0, s1 = v1;
#pragma unroll
  for (int d = 1; d < 64; d <<= 1){
    int n0 = __shfl_up(s0, d); if (lane >= d) s0 += n0;
    int n1 = __shfl_up(s1, d); if (lane >= d) s1 += n1;
  }
  const int tot0 = __shfl(s0, 63);
  offs[lane * NEXP + e]        = s0 - v0;
  offs[(64 + lane) * NEXP + e] = tot0 + s1 - v1;
  if (lane == 63) etot[e] = tot0 + s1;
}

// ---------------- ordered placement + slot map + cw --------------------------
__global__ __launch_bounds__(256) void place_kernel(
    const int* __restrict__ flat_e, const float* __restrict__ topk_p,
    const int* __restrict__ offs, int* __restrict__ entry_slot,
    int* __restrict__ token_of_slot, float* __restrict__ cw_out)
{
  __shared__ int es[256];
  __shared__ float wsh[256];
  const int t = threadIdx.x;
  const int i = blockIdx.x * 256 + t;
  const int e = flat_e[i];
  es[t] = e;
  __syncthreads();
  int local = 0;
  for (int j = 0; j < t; ++j) local += (es[j] == e);
  const int pos = offs[blockIdx.x * NEXP + e] + local;
  const bool valid = pos < CAPC;
  const int slot = e * CAPC + pos;
  entry_slot[i] = valid ? slot : -1;
  if (valid) token_of_slot[slot] = i >> 1;
  const float p = topk_p[i];
  wsh[t] = valid ? p : 0.f;
  __syncthreads();
  const float wme = wsh[t], wo = wsh[t ^ 1];
  cw_out[i] = wme / fmaxf(wme + wo, 1e-12f);
}

// ---------------- build dispatched A (bf16) ----------------------------------
__global__ __launch_bounds__(256) void adisp_kernel(
    const float* __restrict__ x, const int* __restrict__ token_of_slot,
    const int* __restrict__ etot, unsigned short* __restrict__ adisp)
{
  const int slot = blockIdx.x;
  const int e = slot / CAPC, c = slot - e * CAPC;
  int cnt = etot[e]; if (cnt > CAPC) cnt = CAPC;
  if (c >= cnt) return;
  const int tok = token_of_slot[slot];
  const int t = threadIdx.x;
  float4 v = ((const float4*)(x + (size_t)tok * HDIM))[t];
  ushort4 o; o.x = f2bf(v.x); o.y = f2bf(v.y); o.z = f2bf(v.z); o.w = f2bf(v.w);
  ((ushort4*)(adisp + (size_t)slot * HDIM))[t] = o;
}

// B-tile LDS layout (64k x 128n, bf16): 4x16 subtiles, storage block index
//   blk = ((ks*8 + ng)*2 + par)*4 + g ; k = 32ks + 8g + 4par + dk ; n = 16ng + 8h8
//   16B unit index u = blk*8 + dk*2 + h8. gload_lds source address computed per
//   lane by inverting this map (LDS dest linear). tr_read pair per (ks,cg):
//   addr = (ks*8+cg)*1024 + 8*lane, offset:512 for parity 1.
template<int NSTRIDE>
__device__ __forceinline__ int bsrc_off(int u){
  int h8 = u & 1, dk = (u >> 1) & 3, blk = u >> 3;
  int g = blk & 3, par = (blk >> 2) & 1, ng = (blk >> 3) & 7, ks = blk >> 6;
  int k = 32 * ks + 8 * g + 4 * par + dk;
  int n = ng * 16 + h8 * 8;
  return k * NSTRIDE + n;
}

// ---------------- gemm1: fused g,u = A*Wg, A*Wu ; h = silu(g)*u (bf16) -------
__global__ __launch_bounds__(256) void gemm1_kernel(
    const unsigned short* __restrict__ adisp,
    const unsigned short* __restrict__ wgb, const unsigned short* __restrict__ wub,
    unsigned short* __restrict__ hbuf)
{
  __shared__ unsigned short As[128 * 64];    // swizzled row-major [row][j^(row&7)]
  __shared__ unsigned short Bgs[64 * 128];   // subtiled for tr_b16 reads
  __shared__ unsigned short Bus[64 * 128];
  const int bb = blockIdx.x;
  const int lb = (bb & 7) * 160 + (bb >> 3);         // 1280 blocks, 1280%8==0
  const int e = lb / 20; const int r2 = lb - e * 20;
  const int nt = r2 / 5, mt = r2 - nt * 5;           // mt innermost: 5 blocks share B
  const int t = threadIdx.x, w = t >> 6, lane = t & 63;
  const int wr = w >> 1, wc = w & 1;
  const size_t arow0 = (size_t)e * CAPC + (size_t)mt * 128;
  const unsigned short* abase = adisp + arow0 * HDIM;
  const unsigned short* wgp = wgb + (size_t)e * HDIM * IDIM + nt * 128;
  const unsigned short* wup = wub + (size_t)e * HDIM * IDIM + nt * 128;

  int aoff[4], boff[4];
#pragma unroll
  for (int rr = 0; rr < 4; ++rr){
    int c = rr * 256 + t;
    int row = c >> 3;
    int jsrc = (c & 7) ^ (row & 7);
    aoff[rr] = row * HDIM + jsrc * 8;
    boff[rr] = bsrc_off<IDIM>(c);
  }

  f32x4 accg[4][4], accu[4][4];
#pragma unroll
  for (int i = 0; i < 4; ++i)
#pragma unroll
    for (int j = 0; j < 4; ++j)
#pragma unroll
      for (int q = 0; q < 4; ++q){ accg[i][j][q] = 0.f; accu[i][j][q] = 0.f; }

  for (int kb = 0; kb < HDIM; kb += 64){
    __syncthreads();
#pragma unroll
    for (int rr = 0; rr < 4; ++rr)
      gload_lds16(abase + aoff[rr] + kb, &As[(rr * 256 + w * 64) * 8]);
#pragma unroll
    for (int rr = 0; rr < 4; ++rr)
      gload_lds16(wgp + boff[rr] + kb * IDIM, &Bgs[(rr * 256 + w * 64) * 8]);
#pragma unroll
    for (int rr = 0; rr < 4; ++rr)
      gload_lds16(wup + boff[rr] + kb * IDIM, &Bus[(rr * 256 + w * 64) * 8]);
    __syncthreads();

    const unsigned bg0 = ldsoff(Bgs), bu0 = ldsoff(Bus);
#pragma unroll
    for (int ks = 0; ks < 2; ++ks){
      bf16x8 af[4];
#pragma unroll
      for (int m = 0; m < 4; ++m){
        int row = wr * 64 + m * 16 + (lane & 15);
        int j = ks * 4 + (lane >> 4);
        af[m] = *(const bf16x8*)&As[row * 64 + ((j ^ (row & 7)) * 8)];
      }
      bf16x8 bfr[4];
#pragma unroll
      for (int n = 0; n < 4; ++n){
        unsigned ao = (unsigned)((ks * 8 + wc * 4 + n) * 1024 + lane * 8);
        short4v l0, l1;
        trread2(bg0 + ao, l0, l1);
        bfr[n] = __builtin_shufflevector(l0, l1, 0,1,2,3,4,5,6,7);
      }
      asm volatile("s_waitcnt lgkmcnt(0)" ::: "memory");
      __builtin_amdgcn_sched_barrier(0);
#pragma unroll
      for (int m = 0; m < 4; ++m)
#pragma unroll
        for (int n = 0; n < 4; ++n)
          accg[m][n] = __builtin_amdgcn_mfma_f32_16x16x32_bf16(af[m], bfr[n], accg[m][n], 0, 0, 0);
#pragma unroll
      for (int n = 0; n < 4; ++n){
        unsigned ao = (unsigned)((ks * 8 + wc * 4 + n) * 1024 + lane * 8);
        short4v l0, l1;
        trread2(bu0 + ao, l0, l1);
        bfr[n] = __builtin_shufflevector(l0, l1, 0,1,2,3,4,5,6,7);
      }
      asm volatile("s_waitcnt lgkmcnt(0)" ::: "memory");
      __builtin_amdgcn_sched_barrier(0);
#pragma unroll
      for (int m = 0; m < 4; ++m)
#pragma unroll
        for (int n = 0; n < 4; ++n)
          accu[m][n] = __builtin_amdgcn_mfma_f32_16x16x32_bf16(af[m], bfr[n], accu[m][n], 0, 0, 0);
    }
  }
  // epilogue: h = silu(g)*u -> bf16
#pragma unroll
  for (int m = 0; m < 4; ++m)
#pragma unroll
    for (int n = 0; n < 4; ++n)
#pragma unroll
      for (int q = 0; q < 4; ++q){
        int row = wr * 64 + m * 16 + (lane >> 4) * 4 + q;
        int col = nt * 128 + wc * 64 + n * 16 + (lane & 15);
        float gv = accg[m][n][q], uv = accu[m][n][q];
        float hv = gv / (1.f + expf(-gv)) * uv;
        hbuf[(arow0 + row) * IDIM + col] = f2bf(hv);
      }
}

// ---------------- gemm2: eo = h * Wd (bf16 out) ------------------------------
__global__ __launch_bounds__(256) void gemm2_kernel(
    const unsigned short* __restrict__ hbuf,
    const unsigned short* __restrict__ wdb,
    unsigned short* __restrict__ eo)
{
  __shared__ unsigned short As[128 * 64];
  __shared__ unsigned short Bs[64 * 128];
  const int bb = blockIdx.x;
  const int lb = (bb & 7) * 320 + (bb >> 3);         // 2560 blocks, 2560%8==0
  const int e = lb / 40; const int r2 = lb - e * 40;
  const int nt = r2 / 5, mt = r2 - nt * 5;
  const int t = threadIdx.x, w = t >> 6, lane = t & 63;
  const int wr = w >> 1, wc = w & 1;
  const size_t arow0 = (size_t)e * CAPC + (size_t)mt * 128;
  const unsigned short* abase = hbuf + arow0 * IDIM;
  const unsigned short* wdp = wdb + (size_t)e * IDIM * HDIM + nt * 128;

  int aoff[4], boff[4];
#pragma unroll
  for (int rr = 0; rr < 4; ++rr){
    int c = rr * 256 + t;
    int row = c >> 3;
    int jsrc = (c & 7) ^ (row & 7);
    aoff[rr] = row * IDIM + jsrc * 8;
    boff[rr] = bsrc_off<HDIM>(c);
  }

  f32x4 acc[4][4];
#pragma unroll
  for (int i = 0; i < 4; ++i)
#pragma unroll
    for (int j = 0; j < 4; ++j)
#pragma unroll
      for (int q = 0; q < 4; ++q) acc[i][j][q] = 0.f;

  for (int kb = 0; kb < IDIM; kb += 64){
    __syncthreads();
#pragma unroll
    for (int rr = 0; rr < 4; ++rr)
      gload_lds16(abase + aoff[rr] + kb, &As[(rr * 256 + w * 64) * 8]);
#pragma unroll
    for (int rr = 0; rr < 4; ++rr)
      gload_lds16(wdp + boff[rr] + kb * HDIM, &Bs[(rr * 256 + w * 64) * 8]);
    __syncthreads();

    const unsigned b0a = ldsoff(Bs);
#pragma unroll
    for (int ks = 0; ks < 2; ++ks){
      bf16x8 af[4];
#pragma unroll
      for (int m = 0; m < 4; ++m){
        int row = wr * 64 + m * 16 + (lane & 15);
        int j = ks * 4 + (lane >> 4);
        af[m] = *(const bf16x8*)&As[row * 64 + ((j ^ (row & 7)) * 8)];
      }
      bf16x8 bfr[4];
#pragma unroll
      for (int n = 0; n < 4; ++n){
        unsigned ao = (unsigned)((ks * 8 + wc * 4 + n) * 1024 + lane * 8);
        short4v l0, l1;
        trread2(b0a + ao, l0, l1);
        bfr[n] = __builtin_shufflevector(l0, l1, 0,1,2,3,4,5,6,7);
      }
      asm volatile("s_waitcnt lgkmcnt(0)" ::: "memory");
      __builtin_amdgcn_sched_barrier(0);
#pragma unroll
      for (int m = 0; m < 4; ++m)
#pragma unroll
        for (int n = 0; n < 4; ++n)
          acc[m][n] = __builtin_amdgcn_mfma_f32_16x16x32_bf16(af[m], bfr[n], acc[m][n], 0, 0, 0);
    }
  }
#pragma unroll
  for (int m = 0; m < 4; ++m)
#pragma unroll
    for (int n = 0; n < 4; ++n)
#pragma unroll
      for (int q = 0; q < 4; ++q){
        int row = wr * 64 + m * 16 + (lane >> 4) * 4 + q;
        int col = nt * 128 + wc * 64 + n * 16 + (lane & 15);
        eo[(arow0 + row) * HDIM + col] = f2bf(acc[m][n][q]);
      }
}

// ---------------- combine: out[s] = sum_k cw[s,k] * eo[slot(s,k)] ------------
__global__ __launch_bounds__(256) void combine_kernel(
    const unsigned short* __restrict__ eo, const int* __restrict__ entry_slot,
    const float* __restrict__ cw, float* __restrict__ out)
{
  const int s = blockIdx.x, t = threadIdx.x;
  const int s0 = entry_slot[2 * s], s1 = entry_slot[2 * s + 1];
  const float w0 = cw[2 * s], w1 = cw[2 * s + 1];
  const int c = t * 4;
  float r0 = 0.f, r1 = 0.f, r2 = 0.f, r3 = 0.f;
  if (s0 >= 0){
    ushort4 vq = *(const ushort4*)&eo[(size_t)s0 * HDIM + c];
    r0 += w0 * bf2f(vq.x); r1 += w0 * bf2f(vq.y); r2 += w0 * bf2f(vq.z); r3 += w0 * bf2f(vq.w);
  }
  if (s1 >= 0){
    ushort4 vq = *(const ushort4*)&eo[(size_t)s1 * HDIM + c];
    r0 += w1 * bf2f(vq.x); r1 += w1 * bf2f(vq.y); r2 += w1 * bf2f(vq.z); r3 += w1 * bf2f(vq.w);
  }
  ((float4*)(out + (size_t)s * HDIM))[t] = make_float4(r0, r1, r2, r3);
}

extern "C" void kernel_launch(void* const* d_in, const int* in_sizes, int n_in,
                              void* d_out, int out_size, void* d_ws, size_t ws_size,
                              hipStream_t stream) {
  (void)in_sizes; (void)n_in; (void)out_size; (void)ws_size;
  const float* x     = (const float*)d_in[0];
  const float* wgate = (const float*)d_in[1];
  const float* wg    = (const float*)d_in[2];
  const float* wu    = (const float*)d_in[3];
  const float* wd    = (const float*)d_in[4];

  float* out        = (float*)d_out;                         // [S,H]
  float* cw_out     = out + (size_t)S_TOK * HDIM;            // [S,2]
  float* rl_out     = cw_out + (size_t)S_TOK * 2;            // [1]
  float* logits_out = rl_out + 1;                            // [S,64]

  char* w8 = (char*)d_ws;
  size_t off = 0;
  auto alloc = [&](size_t bytes){ size_t r = off; off += (bytes + 255) & ~(size_t)255; return r; };
  int*   flat_e_ws        = (int*)  (w8 + alloc((size_t)32768 * 4));
  float* topk_p_ws        = (float*)(w8 + alloc((size_t)32768 * 4));
  int*   counts_ws        = (int*)  (w8 + alloc((size_t)NCHUNK * NEXP * 4));
  int*   offs_ws          = (int*)  (w8 + alloc((size_t)NCHUNK * NEXP * 4));
  int*   etot_ws          = (int*)  (w8 + alloc((size_t)NEXP * 4));
  int*   entry_slot_ws    = (int*)  (w8 + alloc((size_t)32768 * 4));
  int*   token_of_slot_ws = (int*)  (w8 + alloc((size_t)NEXP * CAPC * 4));
  unsigned short* hbuf_ws = (unsigned short*)(w8 + alloc((size_t)NEXP * CAPC * IDIM * 2));
  unsigned short* adisp_ws= (unsigned short*)(w8 + alloc((size_t)NEXP * CAPC * HDIM * 2));
  unsigned short* wbfA_ws = (unsigned short*)(w8 + alloc((size_t)NEXP * HDIM * IDIM * 2));
  unsigned short* wbfU_ws = (unsigned short*)(w8 + alloc((size_t)NEXP * HDIM * IDIM * 2));
  unsigned short* eo_ws   = adisp_ws;   // alias: adisp dead after gemm1

  const int W8N = NEXP * HDIM * IDIM / 8;   // 4,194,304 16B units per weight

  gate_kernel   <<<S_TOK / 4, 256, 0, stream>>>(x, wgate, logits_out, topk_p_ws, flat_e_ws, rl_out);
  hist_kernel   <<<NCHUNK,    256, 0, stream>>>(flat_e_ws, counts_ws);
  offsets_kernel<<<16,        256, 0, stream>>>(counts_ws, offs_ws, etot_ws);
  place_kernel  <<<NCHUNK,    256, 0, stream>>>(flat_e_ws, topk_p_ws, offs_ws,
                                                entry_slot_ws, token_of_slot_ws, cw_out);
  adisp_kernel  <<<NEXP * CAPC, 256, 0, stream>>>(x, token_of_slot_ws, etot_ws, adisp_ws);
  wcvt_kernel   <<<2048, 256, 0, stream>>>(wg, wbfA_ws, W8N);
  wcvt_kernel   <<<2048, 256, 0, stream>>>(wu, wbfU_ws, W8N);
  gemm1_kernel  <<<NEXP * 20, 256, 0, stream>>>(adisp_ws, wbfA_ws, wbfU_ws, hbuf_ws);
  wcvt_kernel   <<<2048, 256, 0, stream>>>(wd, wbfA_ws, W8N);   // reuse wg-bf16 buffer
  gemm2_kernel  <<<NEXP * 40, 256, 0, stream>>>(hbuf_ws, wbfA_ws, eo_ws);
  combine_kernel<<<S_TOK,     256, 0, stream>>>(eo_ws, entry_slot_ws, cw_out, out);
}